// Round 3
// baseline (313.562 us; speedup 1.0000x reference)
//
#include <hip/hip_runtime.h>

typedef unsigned short u16;
typedef __attribute__((ext_vector_type(8))) short bf16x8;   // 8 bf16 in 4 VGPRs
typedef __attribute__((ext_vector_type(4))) float floatx4;

__device__ __forceinline__ u16 f2b(float f) {
    union { float f; unsigned u; } v; v.f = f;
    return (u16)((v.u + 0x7FFFu + ((v.u >> 16) & 1u)) >> 16);   // RNE
}
__device__ __forceinline__ float lo16f(unsigned u) {
    union { unsigned u; float f; } v; v.u = u << 16; return v.f;
}
__device__ __forceinline__ float hi16f(unsigned u) {
    union { unsigned u; float f; } v; v.u = u & 0xFFFF0000u; return v.f;
}

#if defined(__has_builtin)
#if __has_builtin(__builtin_amdgcn_cvt_pk_bf16_f32)
#define PK_HW 1
#endif
#endif

// pack 2 floats -> 2 bf16 (RNE), element0 = a (low u16)
__device__ __forceinline__ unsigned pk2(float a, float b) {
#ifdef PK_HW
    auto r = __builtin_amdgcn_cvt_pk_bf16_f32(a, b);
    unsigned u; __builtin_memcpy(&u, &r, 4); return u;
#else
    union { float f; unsigned u; } x, y; x.f = a; y.f = b;
    unsigned ua = x.u + 0x7FFFu + ((x.u >> 16) & 1u);
    unsigned ub = y.u + 0x7FFFu + ((y.u >> 16) & 1u);
    return __builtin_amdgcn_perm(ub, ua, 0x07060302u);  // {ub.hi16, ua.hi16}
#endif
}

// ---------------- P0: weight prep -> MFMA B-fragment tables (bf16) ----------------
// Frag entry (s, nt, lane, j) = B[kk = s*32 + (lane>>4)*8 + j][n = nt*16 + (lane&15)]
// W2f: [k2][s<8][nt<16][l][8]; Wo1f: [s<9][nt<16][l][8] (K pad 280->288);
// Wo2f: [s<8][nt<16][l][8];    Wo3f: [s<8][nt<2][l][8]  (N pad 24->32)
// LDS-tile transpose: coalesced loads, padded-stride LDS, coalesced uint4 stores.
__global__ void prep_weights(const float* __restrict__ Wm2, const float* __restrict__ Wo1,
                             const float* __restrict__ Wo2, const float* __restrict__ Wo3,
                             u16* __restrict__ W2f, u16* __restrict__ Wo1f,
                             u16* __restrict__ Wo2f, u16* __restrict__ Wo3f) {
    __shared__ float tile[32 * 257];
    __shared__ float t3[256 * 25];
    int id = blockIdx.x;
    int tid = threadIdx.x;
    if (id < 33) {
        const float* src; u16* dst; int s, Ksrc;
        if (id < 16)      { int k = id >> 3; s = id & 7; src = Wm2 + k * 65536; dst = W2f + k * 65536; Ksrc = 256; }
        else if (id < 25) { s = id - 16; src = Wo1; dst = Wo1f; Ksrc = 280; }
        else              { s = id - 25; src = Wo2; dst = Wo2f; Ksrc = 256; }
        int kk0 = s * 32;
        for (int t = tid; t < 32 * 256; t += 256) {
            int r = t >> 8, c = t & 255;
            tile[r * 257 + c] = (kk0 + r < Ksrc) ? src[(size_t)(kk0 + r) * 256 + c] : 0.f;
        }
        __syncthreads();
#pragma unroll
        for (int it = 0; it < 4; it++) {
            int t = tid + 256 * it;                  // 0..1023 = (nt, l)
            int nt = t >> 6, l = t & 63;
            int n = nt * 16 + (l & 15), q = l >> 4;
            unsigned o[4];
#pragma unroll
            for (int jp = 0; jp < 4; jp++)
                o[jp] = pk2(tile[(q * 8 + jp * 2) * 257 + n], tile[(q * 8 + jp * 2 + 1) * 257 + n]);
            *(uint4*)(dst + ((size_t)(s * 16 + nt)) * 512 + l * 8) = *(uint4*)o;
        }
    } else {
        for (int t = tid; t < 256 * 24; t += 256) {
            int r = t / 24, c = t - r * 24;
            t3[r * 25 + c] = Wo3[t];
        }
        __syncthreads();
#pragma unroll
        for (int it = 0; it < 4; it++) {
            int e = tid + 256 * it;                  // 0..1023 = ((s*2+nt)*64 + l)
            int s3 = e >> 7, nt = (e >> 6) & 1, l = e & 63;
            int n = nt * 16 + (l & 15), q = l >> 4;
            float v[8];
#pragma unroll
            for (int j = 0; j < 8; j++) {
                int kk = s3 * 32 + q * 8 + j;
                v[j] = (n < 24) ? t3[kk * 25 + n] : 0.f;
            }
            unsigned o[4];
#pragma unroll
            for (int jp = 0; jp < 4; jp++) o[jp] = pk2(v[jp * 2], v[jp * 2 + 1]);
            *(uint4*)(Wo3f + (size_t)e * 8) = *(uint4*)o;
        }
    }
}

// ---------------- P1: x0 + u1 (frag order) / u2 (row order) ----------------
// u1[b,n,k,h] = x0[b,n]·W1[k][0:24,h]; u2 = x0·W1[k][24:48,h]+b1 (bias folded)
// u1f layout: [b][k][frag(s*4+rt)*64+lane_f][8] so edge_kernel stage loads are coalesced.
__global__ void compute_u(const float* __restrict__ data, const float* __restrict__ act,
                          const float* __restrict__ Wm1, const float* __restrict__ bm1,
                          float* __restrict__ x0, u16* __restrict__ u1f, u16* __restrict__ u2f) {
    int r0 = blockIdx.x * 16;
    int b = r0 >> 6;
    __shared__ float xs[16][24];
    int tid = threadIdx.x;
    for (int idx = tid; idx < 16 * 24; idx += 256) {
        int rr = idx / 24, d = idx - rr * 24;
        int r = r0 + rr;
        float v = (d < 16) ? data[(r * 2) * 16 + d]       // t=0 only (output keeps t=0)
                           : act[(r * 2) * 8 + (d - 16)];
        xs[rr][d] = v;
        x0[r * 24 + d] = v;
    }
    __syncthreads();
    int h = tid;
    float acc[4][16];
#pragma unroll
    for (int q = 0; q < 4; q++)
#pragma unroll
        for (int rr = 0; rr < 16; rr++) acc[q][rr] = 0.f;
#pragma unroll
    for (int d = 0; d < 24; d++) {
        float w10 = Wm1[(0 * 48 + d) * 256 + h];
        float w11 = Wm1[(1 * 48 + d) * 256 + h];
        float w20 = Wm1[(0 * 48 + 24 + d) * 256 + h];
        float w21 = Wm1[(1 * 48 + 24 + d) * 256 + h];
#pragma unroll
        for (int rr = 0; rr < 16; rr++) {
            float x = xs[rr][d];
            acc[0][rr] += x * w10;
            acc[1][rr] += x * w11;
            acc[2][rr] += x * w20;
            acc[3][rr] += x * w21;
        }
    }
    float bb0 = bm1[h], bb1 = bm1[256 + h];
    int s = h >> 5, q = (h >> 3) & 3, j = h & 7;
#pragma unroll
    for (int rr = 0; rr < 16; rr++) {
        int r = r0 + rr;
        int row = r & 63;
        int lane_f = (row & 15) | (q << 4);
        size_t e8 = ((size_t)((s * 4 + (row >> 4)) * 64 + lane_f)) * 8 + j;
        u1f[(size_t)(b * 2 + 0) * 16384 + e8] = f2b(acc[0][rr]);
        u1f[(size_t)(b * 2 + 1) * 16384 + e8] = f2b(acc[1][rr]);
        u2f[((size_t)r * 2 + 0) * 256 + h] = f2b(acc[2][rr] + bb0);
        u2f[((size_t)r * 2 + 1) * 256 + h] = f2b(acc[3][rr] + bb1);
    }
}

// ---------------- K3: edge MLP layer-2 + weighted aggregate ----------------
// Block = (b, 8 receivers). B fragments VGPR-resident per k; bias folded into acc init;
// A staged per-i in fragment order (conflict-free); agg accumulated over k in LDS.
__global__ __launch_bounds__(256, 2) void edge_kernel(
    const u16* __restrict__ u1f, const u16* __restrict__ u2f, const float* __restrict__ edges,
    const u16* __restrict__ W2f, const float* __restrict__ bm2, float* __restrict__ agg) {
    int blk = blockIdx.x;
    int b = blk >> 3;
    int i0 = (blk & 7) * 8;
    __shared__ __align__(16) u16 Af[16384];       // 32 KB: [s<8][rt<4][lane][8]
    __shared__ __align__(16) u16 u2s[8 * 256];    // 4 KB bf16
    __shared__ float w_s[8 * 64];                 // 2 KB
    __shared__ float aggs[8 * 256];               // 8 KB
    int tid = threadIdx.x;
    int lane = tid & 63, wave = tid >> 6;
    const int lhi = lane >> 4;
    const int colBase = wave * 64;

#pragma unroll
    for (int t = tid; t < 2048; t += 256) aggs[t] = 0.f;

#pragma unroll 1
    for (int k = 0; k < 2; k++) {
        {   // stage u2 rows (8 x 256 bf16, 256 uint4 = one per thread)
            int ii = tid >> 5, u4 = tid & 31;
            *(uint4*)&u2s[ii * 256 + u4 * 8] =
                *(const uint4*)&u2f[((size_t)((b * 64 + i0 + ii) * 2 + k)) * 256 + u4 * 8];
        }
#pragma unroll
        for (int it = 0; it < 2; it++) {          // stage edge weights
            int t = tid + 256 * it;
            int ii = t >> 6, j = t & 63;
            int ia = i0 + ii;
            float w = 0.f;
            if (j != ia) {
                int jj = j - (j > ia ? 1 : 0);
                w = edges[((size_t)b * 4032 + (size_t)ia * 63 + jj) * 2 + k];
            }
            w_s[t] = w;
        }
        float bb[4];
#pragma unroll
        for (int ct = 0; ct < 4; ct++) bb[ct] = bm2[k * 256 + colBase + ct * 16 + (lane & 15)];
        bf16x8 Breg[8][4];                        // wave's B cols, VGPR-resident
        {
            const u16* Wb = W2f + (size_t)k * 65536 + (size_t)wave * 2048 + lane * 8;
#pragma unroll
            for (int s = 0; s < 8; s++)
#pragma unroll
                for (int ct = 0; ct < 4; ct++)
                    Breg[s][ct] = *(const bf16x8*)(Wb + s * 8192 + ct * 512);
        }
        const u16* u1bk = u1f + (size_t)(b * 2 + k) * 16384 + wave * 512 + lane * 8;
        __syncthreads();

#pragma unroll 1
        for (int il = 0; il < 8; il++) {
            // stage Af = relu(u1 + u2[il]); thread covers frag (s=it, rt=wave)
#pragma unroll
            for (int it = 0; it < 8; it++) {
                uint4 av = *(const uint4*)(u1bk + it * 2048);
                int c0 = it * 32 + lhi * 8;
                uint4 uv = *(const uint4*)&u2s[il * 256 + c0];
                unsigned o[4];
                o[0] = pk2(fmaxf(lo16f(av.x) + lo16f(uv.x), 0.f), fmaxf(hi16f(av.x) + hi16f(uv.x), 0.f));
                o[1] = pk2(fmaxf(lo16f(av.y) + lo16f(uv.y), 0.f), fmaxf(hi16f(av.y) + hi16f(uv.y), 0.f));
                o[2] = pk2(fmaxf(lo16f(av.z) + lo16f(uv.z), 0.f), fmaxf(hi16f(av.z) + hi16f(uv.z), 0.f));
                o[3] = pk2(fmaxf(lo16f(av.w) + lo16f(uv.w), 0.f), fmaxf(hi16f(av.w) + hi16f(uv.w), 0.f));
                *(uint4*)&Af[it * 2048 + wave * 512 + lane * 8] = *(uint4*)o;
            }
            __syncthreads();

            floatx4 acc[4][4];                    // bias pre-folded
#pragma unroll
            for (int rt = 0; rt < 4; rt++)
#pragma unroll
                for (int ct = 0; ct < 4; ct++) {
                    acc[rt][ct][0] = bb[ct]; acc[rt][ct][1] = bb[ct];
                    acc[rt][ct][2] = bb[ct]; acc[rt][ct][3] = bb[ct];
                }
#pragma unroll
            for (int s = 0; s < 8; s++) {
                bf16x8 af[4];
#pragma unroll
                for (int rt = 0; rt < 4; rt++)
                    af[rt] = *(const bf16x8*)&Af[(s * 4 + rt) * 512 + lane * 8];
#pragma unroll
                for (int rt = 0; rt < 4; rt++)
#pragma unroll
                    for (int ct = 0; ct < 4; ct++)
                        acc[rt][ct] = __builtin_amdgcn_mfma_f32_16x16x32_bf16(
                            af[rt], Breg[s][ct], acc[rt][ct], 0, 0, 0);
            }
            // epilogue: sum_j relu(C)*w  (C: col=lane&15, row=quad*4+reg)
            float4 wv[4];
#pragma unroll
            for (int rt = 0; rt < 4; rt++)
                wv[rt] = *(const float4*)&w_s[il * 64 + rt * 16 + lhi * 4];
#pragma unroll
            for (int ct = 0; ct < 4; ct++) {
                float p = 0.f;
#pragma unroll
                for (int rt = 0; rt < 4; rt++) {
                    p += fmaxf(acc[rt][ct][0], 0.f) * wv[rt].x;
                    p += fmaxf(acc[rt][ct][1], 0.f) * wv[rt].y;
                    p += fmaxf(acc[rt][ct][2], 0.f) * wv[rt].z;
                    p += fmaxf(acc[rt][ct][3], 0.f) * wv[rt].w;
                }
                p += __shfl_xor(p, 16, 64);
                p += __shfl_xor(p, 32, 64);
                if (lhi == 0) aggs[il * 256 + colBase + ct * 16 + lane] += p;  // wave-private cols
            }
            __syncthreads();
        }
    }
    for (int t = tid; t < 2048; t += 256)
        agg[((size_t)(b * 64 + i0 + (t >> 8))) * 256 + (t & 255)] = aggs[t];
}

// ---------------- K4: out-MLP (280->256->256->24) + residual + q, one block per b ----------------
__global__ void out_mlp(const float* __restrict__ x0, const float* __restrict__ agg,
                        const u16* __restrict__ Wo1f, const u16* __restrict__ Wo2f,
                        const u16* __restrict__ Wo3f,
                        const float* __restrict__ bo1, const float* __restrict__ bo2,
                        const float* __restrict__ bo3,
                        const float* __restrict__ Wq2, const float* __restrict__ bq2,
                        const float* __restrict__ Wq3, const float* __restrict__ bq3,
                        float* __restrict__ out) {
    int b = blockIdx.x;
    int tid = threadIdx.x;
    int lane = tid & 63, wave = tid >> 6;
    const int colBase = wave * 64;
    const int lhi = lane >> 4;
    __shared__ __align__(16) u16 A1f[2304 * 8];
    __shared__ __align__(16) u16 A2f[2048 * 8];
    __shared__ __align__(16) u16 h2f[2048 * 8];
    __shared__ float qs[4];

#pragma unroll
    for (int it = 0; it < 9; it++) {
        int fi = tid + 256 * it;
        int lane_f = fi & 63, frag = fi >> 6;
        int s = frag >> 2, rt = frag & 3;
        int m = rt * 16 + (lane_f & 15);
        int c0 = s * 32 + (lane_f >> 4) * 8;
        float vals[8];
        if (c0 < 24) {
            const float4* xr = (const float4*)(x0 + (b * 64 + m) * 24 + c0);
            float4 a = xr[0], c = xr[1];
            vals[0] = a.x; vals[1] = a.y; vals[2] = a.z; vals[3] = a.w;
            vals[4] = c.x; vals[5] = c.y; vals[6] = c.z; vals[7] = c.w;
        } else if (c0 < 280) {
            const float4* ar = (const float4*)(agg + ((size_t)(b * 64 + m)) * 256 + (c0 - 24));
            float4 a = ar[0], c = ar[1];
            vals[0] = a.x; vals[1] = a.y; vals[2] = a.z; vals[3] = a.w;
            vals[4] = c.x; vals[5] = c.y; vals[6] = c.z; vals[7] = c.w;
        } else {
#pragma unroll
            for (int q = 0; q < 8; q++) vals[q] = 0.f;
        }
        unsigned o[4];
#pragma unroll
        for (int jp = 0; jp < 4; jp++) o[jp] = pk2(vals[jp * 2], vals[jp * 2 + 1]);
        *(uint4*)(&A1f[fi * 8]) = *(uint4*)o;
    }
    __syncthreads();

    floatx4 acc[4][4];
#pragma unroll
    for (int rt = 0; rt < 4; rt++)
#pragma unroll
        for (int ct = 0; ct < 4; ct++)
#pragma unroll
            for (int q = 0; q < 4; q++) acc[rt][ct][q] = 0.f;
#pragma unroll
    for (int step = 0; step < 9; step++) {
        const u16* Wk = Wo1f + ((size_t)(step * 16 + wave * 4)) * 512;
        bf16x8 bfr[4], af[4];
#pragma unroll
        for (int ct = 0; ct < 4; ct++) bfr[ct] = *(const bf16x8*)(Wk + ct * 512 + lane * 8);
#pragma unroll
        for (int rt = 0; rt < 4; rt++) af[rt] = *(const bf16x8*)(&A1f[((step * 4 + rt) * 64 + lane) * 8]);
#pragma unroll
        for (int rt = 0; rt < 4; rt++)
#pragma unroll
            for (int ct = 0; ct < 4; ct++)
                acc[rt][ct] = __builtin_amdgcn_mfma_f32_16x16x32_bf16(af[rt], bfr[ct], acc[rt][ct], 0, 0, 0);
    }
#pragma unroll
    for (int ct = 0; ct < 4; ct++) {
        int col = colBase + ct * 16 + (lane & 15);
        float bbv = bo1[col];
        int s2 = col >> 5, jj = col & 7, lf_hi = ((col >> 3) & 3) << 4;
#pragma unroll
        for (int rt = 0; rt < 4; rt++)
#pragma unroll
            for (int reg = 0; reg < 4; reg++) {
                int row = rt * 16 + lhi * 4 + reg;
                int lane_f = (row & 15) | lf_hi;
                A2f[((s2 * 4 + rt) * 64 + lane_f) * 8 + jj] = f2b(fmaxf(acc[rt][ct][reg] + bbv, 0.f));
            }
    }
    __syncthreads();

#pragma unroll
    for (int rt = 0; rt < 4; rt++)
#pragma unroll
        for (int ct = 0; ct < 4; ct++)
#pragma unroll
            for (int q = 0; q < 4; q++) acc[rt][ct][q] = 0.f;
#pragma unroll
    for (int step = 0; step < 8; step++) {
        const u16* Wk = Wo2f + ((size_t)(step * 16 + wave * 4)) * 512;
        bf16x8 bfr[4], af[4];
#pragma unroll
        for (int ct = 0; ct < 4; ct++) bfr[ct] = *(const bf16x8*)(Wk + ct * 512 + lane * 8);
#pragma unroll
        for (int rt = 0; rt < 4; rt++) af[rt] = *(const bf16x8*)(&A2f[((step * 4 + rt) * 64 + lane) * 8]);
#pragma unroll
        for (int rt = 0; rt < 4; rt++)
#pragma unroll
            for (int ct = 0; ct < 4; ct++)
                acc[rt][ct] = __builtin_amdgcn_mfma_f32_16x16x32_bf16(af[rt], bfr[ct], acc[rt][ct], 0, 0, 0);
    }
#pragma unroll
    for (int ct = 0; ct < 4; ct++) {
        int col = colBase + ct * 16 + (lane & 15);
        float bbv = bo2[col];
        int s2 = col >> 5, jj = col & 7, lf_hi = ((col >> 3) & 3) << 4;
#pragma unroll
        for (int rt = 0; rt < 4; rt++)
#pragma unroll
            for (int reg = 0; reg < 4; reg++) {
                int row = rt * 16 + lhi * 4 + reg;
                int lane_f = (row & 15) | lf_hi;
                h2f[((s2 * 4 + rt) * 64 + lane_f) * 8 + jj] = f2b(fmaxf(acc[rt][ct][reg] + bbv, 0.f));
            }
    }
    __syncthreads();

    floatx4 acc3[2];
#pragma unroll
    for (int ct = 0; ct < 2; ct++)
#pragma unroll
        for (int q = 0; q < 4; q++) acc3[ct][q] = 0.f;
#pragma unroll
    for (int step = 0; step < 8; step++) {
        bf16x8 af = *(const bf16x8*)(&h2f[((step * 4 + wave) * 64 + lane) * 8]);
#pragma unroll
        for (int ct = 0; ct < 2; ct++) {
            bf16x8 bfr = *(const bf16x8*)(Wo3f + ((size_t)(step * 2 + ct)) * 512 + lane * 8);
            acc3[ct] = __builtin_amdgcn_mfma_f32_16x16x32_bf16(af, bfr, acc3[ct], 0, 0, 0);
        }
    }
    float pr[4];
#pragma unroll
    for (int reg = 0; reg < 4; reg++) {
        float p = 0.f;
#pragma unroll
        for (int ct = 0; ct < 2; ct++) {
            int col = ct * 16 + (lane & 15);
            if (col < 24) {
                int row = wave * 16 + lhi * 4 + reg;
                float val = acc3[ct][reg] + bo3[col] + x0[(b * 64 + row) * 24 + col];
                p += val * Wq2[col];
            }
        }
        pr[reg] = p;
    }
#pragma unroll
    for (int off = 1; off <= 8; off <<= 1)
#pragma unroll
        for (int reg = 0; reg < 4; reg++) pr[reg] += __shfl_xor(pr[reg], off, 64);
    float contrib = 0.f;
    if ((lane & 15) == 0) {
#pragma unroll
        for (int reg = 0; reg < 4; reg++) {
            int row = wave * 16 + lhi * 4 + reg;
            contrib += (pr[reg] + bq2[0]) * Wq3[row];
        }
    }
    contrib += __shfl_xor(contrib, 16, 64);
    contrib += __shfl_xor(contrib, 32, 64);
    if (lane == 0) qs[wave] = contrib;
    __syncthreads();
    if (tid == 0) out[b] = bq3[0] + qs[0] + qs[1] + qs[2] + qs[3];
}

extern "C" void kernel_launch(void* const* d_in, const int* in_sizes, int n_in,
                              void* d_out, int out_size, void* d_ws, size_t ws_size,
                              hipStream_t stream) {
    const float* data = (const float*)d_in[0];
    const float* act  = (const float*)d_in[1];
    const float* edges = (const float*)d_in[2];
    // d_in[3] rel_rec, d_in[4] rel_send, d_in[5] prediction_steps: structure hardcoded (steps=1)
    const float* Wm1 = (const float*)d_in[6];
    const float* bm1 = (const float*)d_in[7];
    const float* Wm2 = (const float*)d_in[8];
    const float* bm2 = (const float*)d_in[9];
    const float* Wo1 = (const float*)d_in[10];
    const float* bo1 = (const float*)d_in[11];
    const float* Wo2 = (const float*)d_in[12];
    const float* bo2 = (const float*)d_in[13];
    const float* Wo3 = (const float*)d_in[14];
    const float* bo3 = (const float*)d_in[15];
    const float* Wq2 = (const float*)d_in[16];
    const float* bq2 = (const float*)d_in[17];
    const float* Wq3 = (const float*)d_in[18];
    const float* bq3 = (const float*)d_in[19];
    float* out = (float*)d_out;

    char* ws = (char*)d_ws;
    size_t off = 0;
    auto carve = [&](size_t bytes) -> void* {
        void* p = ws + off;
        off += (bytes + 255) & ~(size_t)255;
        return p;
    };
    u16*   u1f  = (u16*)carve((size_t)64 * 2 * 16384 * 2);      // 4 MB, frag order
    u16*   u2f  = (u16*)carve((size_t)64 * 64 * 2 * 256 * 2);   // 4 MB
    float* x0   = (float*)carve((size_t)64 * 64 * 24 * 4);
    float* agg  = (float*)carve((size_t)64 * 64 * 256 * 4);     // 4 MB
    u16*   W2f  = (u16*)carve((size_t)2 * 8 * 16 * 64 * 8 * 2);
    u16*   Wo1f = (u16*)carve((size_t)9 * 16 * 64 * 8 * 2);
    u16*   Wo2f = (u16*)carve((size_t)8 * 16 * 64 * 8 * 2);
    u16*   Wo3f = (u16*)carve((size_t)8 * 2 * 64 * 8 * 2);

    prep_weights<<<dim3(34), dim3(256), 0, stream>>>(Wm2, Wo1, Wo2, Wo3, W2f, Wo1f, Wo2f, Wo3f);
    compute_u<<<dim3(256), dim3(256), 0, stream>>>(data, act, Wm1, bm1, x0, u1f, u2f);
    edge_kernel<<<dim3(512), dim3(256), 0, stream>>>(u1f, u2f, edges, W2f, bm2, agg);
    out_mlp<<<dim3(64), dim3(256), 0, stream>>>(x0, agg, Wo1f, Wo2f, Wo3f, bo1, bo2, bo3,
                                                Wq2, bq2, Wq3, bq3, out);
}

// Round 4
// 216.632 us; speedup vs baseline: 1.4474x; 1.4474x over previous
//
#include <hip/hip_runtime.h>

typedef unsigned short u16;
typedef __attribute__((ext_vector_type(8))) short bf16x8;   // 8 bf16 in 4 VGPRs
typedef __attribute__((ext_vector_type(4))) float floatx4;

__device__ __forceinline__ u16 f2b(float f) {
    union { float f; unsigned u; } v; v.f = f;
    return (u16)((v.u + 0x7FFFu + ((v.u >> 16) & 1u)) >> 16);   // RNE
}
__device__ __forceinline__ float lo16f(unsigned u) {
    union { unsigned u; float f; } v; v.u = u << 16; return v.f;
}
__device__ __forceinline__ float hi16f(unsigned u) {
    union { unsigned u; float f; } v; v.u = u & 0xFFFF0000u; return v.f;
}

#if defined(__has_builtin)
#if __has_builtin(__builtin_amdgcn_cvt_pk_bf16_f32)
#define PK_HW 1
#endif
#endif

// pack 2 floats -> 2 bf16 (RNE), element0 = a (low u16)
__device__ __forceinline__ unsigned pk2(float a, float b) {
#ifdef PK_HW
    auto r = __builtin_amdgcn_cvt_pk_bf16_f32(a, b);
    unsigned u; __builtin_memcpy(&u, &r, 4); return u;
#else
    union { float f; unsigned u; } x, y; x.f = a; y.f = b;
    unsigned ua = x.u + 0x7FFFu + ((x.u >> 16) & 1u);
    unsigned ub = y.u + 0x7FFFu + ((y.u >> 16) & 1u);
    return __builtin_amdgcn_perm(ub, ua, 0x07060302u);  // {ub.hi16, ua.hi16}
#endif
}

// ---------------- P0 (fused): weight prep + x0/u1/u2 ----------------
// Blocks 0..33: weight-fragment tables.  Blocks 34..289: compute_u.
// Frag entry (s, nt, lane, j) = B[kk = s*32 + (lane>>4)*8 + j][n = nt*16 + (lane&15)]
// W2f: [k2][s<8][nt<16][l][8]; Wo1f: [s<9][nt<16][l][8] (K pad 280->288);
// Wo2f: [s<8][nt<16][l][8];    Wo3f: [s<8][nt<2][l][8]  (N pad 24->32)
__global__ void prep_and_u(const float* __restrict__ Wm2, const float* __restrict__ Wo1,
                           const float* __restrict__ Wo2, const float* __restrict__ Wo3,
                           u16* __restrict__ W2f, u16* __restrict__ Wo1f,
                           u16* __restrict__ Wo2f, u16* __restrict__ Wo3f,
                           const float* __restrict__ data, const float* __restrict__ act,
                           const float* __restrict__ Wm1, const float* __restrict__ bm1,
                           float* __restrict__ x0, u16* __restrict__ u1, u16* __restrict__ u2) {
    __shared__ float tile[32 * 257];
    __shared__ float t3[256 * 25];
    int id = blockIdx.x;
    int tid = threadIdx.x;
    if (id < 33) {
        const float* src; u16* dst; int s, Ksrc;
        if (id < 16)      { int k = id >> 3; s = id & 7; src = Wm2 + k * 65536; dst = W2f + k * 65536; Ksrc = 256; }
        else if (id < 25) { s = id - 16; src = Wo1; dst = Wo1f; Ksrc = 280; }
        else              { s = id - 25; src = Wo2; dst = Wo2f; Ksrc = 256; }
        int kk0 = s * 32;
        for (int t = tid; t < 32 * 256; t += 256) {
            int r = t >> 8, c = t & 255;
            tile[r * 257 + c] = (kk0 + r < Ksrc) ? src[(size_t)(kk0 + r) * 256 + c] : 0.f;
        }
        __syncthreads();
#pragma unroll
        for (int it = 0; it < 4; it++) {
            int t = tid + 256 * it;                  // 0..1023 = (nt, l)
            int nt = t >> 6, l = t & 63;
            int n = nt * 16 + (l & 15), q = l >> 4;
            unsigned o[4];
#pragma unroll
            for (int jp = 0; jp < 4; jp++)
                o[jp] = pk2(tile[(q * 8 + jp * 2) * 257 + n], tile[(q * 8 + jp * 2 + 1) * 257 + n]);
            *(uint4*)(dst + ((size_t)(s * 16 + nt)) * 512 + l * 8) = *(uint4*)o;
        }
    } else if (id == 33) {
        for (int t = tid; t < 256 * 24; t += 256) {
            int r = t / 24, c = t - r * 24;
            t3[r * 25 + c] = Wo3[t];
        }
        __syncthreads();
#pragma unroll
        for (int it = 0; it < 4; it++) {
            int e = tid + 256 * it;                  // 0..1023 = ((s*2+nt)*64 + l)
            int s3 = e >> 7, nt = (e >> 6) & 1, l = e & 63;
            int n = nt * 16 + (l & 15), q = l >> 4;
            float v[8];
#pragma unroll
            for (int j = 0; j < 8; j++) {
                int kk = s3 * 32 + q * 8 + j;
                v[j] = (n < 24) ? t3[kk * 25 + n] : 0.f;
            }
            unsigned o[4];
#pragma unroll
            for (int jp = 0; jp < 4; jp++) o[jp] = pk2(v[jp * 2], v[jp * 2 + 1]);
            *(uint4*)(Wo3f + (size_t)e * 8) = *(uint4*)o;
        }
    } else {
        // ---- compute_u: u1[b,n,k,h] = x0·W1[k][0:24,h]; u2 = x0·W1[k][24:48,h]+b1 ----
        int r0 = (id - 34) * 16;
        float* xs = tile;                            // reuse LDS (16*24 floats)
        for (int idx = tid; idx < 16 * 24; idx += 256) {
            int rr = idx / 24, d = idx - rr * 24;
            int r = r0 + rr;
            float v = (d < 16) ? data[(r * 2) * 16 + d]       // t=0 only (output keeps t=0)
                               : act[(r * 2) * 8 + (d - 16)];
            xs[rr * 24 + d] = v;
            x0[r * 24 + d] = v;
        }
        __syncthreads();
        int h = tid;
        float acc[4][16];
#pragma unroll
        for (int q = 0; q < 4; q++)
#pragma unroll
            for (int rr = 0; rr < 16; rr++) acc[q][rr] = 0.f;
#pragma unroll
        for (int d = 0; d < 24; d++) {
            float w10 = Wm1[(0 * 48 + d) * 256 + h];
            float w11 = Wm1[(1 * 48 + d) * 256 + h];
            float w20 = Wm1[(0 * 48 + 24 + d) * 256 + h];
            float w21 = Wm1[(1 * 48 + 24 + d) * 256 + h];
#pragma unroll
            for (int rr = 0; rr < 16; rr++) {
                float x = xs[rr * 24 + d];
                acc[0][rr] += x * w10;
                acc[1][rr] += x * w11;
                acc[2][rr] += x * w20;
                acc[3][rr] += x * w21;
            }
        }
        float bb0 = bm1[h], bb1 = bm1[256 + h];
#pragma unroll
        for (int rr = 0; rr < 16; rr++) {
            int r = r0 + rr;
            u1[((size_t)r * 2 + 0) * 256 + h] = f2b(acc[0][rr]);
            u1[((size_t)r * 2 + 1) * 256 + h] = f2b(acc[1][rr]);
            u2[((size_t)r * 2 + 0) * 256 + h] = f2b(acc[2][rr] + bb0);
            u2[((size_t)r * 2 + 1) * 256 + h] = f2b(acc[3][rr] + bb1);
        }
    }
}

// ---------------- K3: edge MLP layer-2 + weighted aggregate (R2 skeleton + VALU diet) ----------------
// block = (b,i). A = relu(u1[b,j,k]+u2[b,i,k]) staged in LDS in A-fragment order
// (conflict-free b128); B fragments loaded per-step global->reg from W2f (L2-hit);
// bias folded into acc init. No barriers inside the 8-step MFMA loop.
__global__ __launch_bounds__(256, 3) void edge_kernel(
    const u16* __restrict__ u1, const u16* __restrict__ u2, const float* __restrict__ edges,
    const u16* __restrict__ W2f, const float* __restrict__ bm2, float* __restrict__ agg) {
    int blk = blockIdx.x;
    int b = blk >> 6, i = blk & 63;
    __shared__ __align__(16) u16 Af[2048 * 8];    // 32 KB: [s<8][rt<4][lane_f][8]
    __shared__ float agg_s[256];                  // wave-private column ranges
    __shared__ float w_s[64];
    int tid = threadIdx.x;
    int lane = tid & 63, wave = tid >> 6;
    agg_s[tid] = 0.f;
    const int colBase = wave * 64;
    const int lhi = lane >> 4;

#pragma unroll 1
    for (int k = 0; k < 2; k++) {
        __syncthreads();                 // all waves done with Af/w_s of prev k
        if (tid < 64) {
            int j = tid;
            float w = 0.f;
            if (j != i) {
                int jj = j - (j > i ? 1 : 0);
                w = edges[((size_t)b * 4032 + (size_t)i * 63 + jj) * 2 + k];
            }
            w_s[j] = w;
        }
        float bb[4];
#pragma unroll
        for (int ct = 0; ct < 4; ct++) bb[ct] = bm2[k * 256 + colBase + ct * 16 + (lane & 15)];
        // stage A in fragment order: entry fi=(frag,lane_f) holds 8 u16
        const u16* u1b = u1 + ((size_t)(b * 128 + k)) * 256;     // + j*512 per row
        const u16* u2row = u2 + ((size_t)(b * 128 + 2 * i + k)) * 256;
#pragma unroll
        for (int it = 0; it < 8; it++) {
            int fi = tid + 256 * it;                // 0..2047
            int lane_f = fi & 63, frag = fi >> 6;   // frag = s*4+rt
            int s = frag >> 2, rt = frag & 3;
            int j = rt * 16 + (lane_f & 15);
            int c0 = s * 32 + (lane_f >> 4) * 8;
            uint4 av = *(const uint4*)(u1b + j * 512 + c0);
            uint4 uv = *(const uint4*)(u2row + c0);
            unsigned o[4];
            o[0] = pk2(fmaxf(lo16f(av.x) + lo16f(uv.x), 0.f), fmaxf(hi16f(av.x) + hi16f(uv.x), 0.f));
            o[1] = pk2(fmaxf(lo16f(av.y) + lo16f(uv.y), 0.f), fmaxf(hi16f(av.y) + hi16f(uv.y), 0.f));
            o[2] = pk2(fmaxf(lo16f(av.z) + lo16f(uv.z), 0.f), fmaxf(hi16f(av.z) + hi16f(uv.z), 0.f));
            o[3] = pk2(fmaxf(lo16f(av.w) + lo16f(uv.w), 0.f), fmaxf(hi16f(av.w) + hi16f(uv.w), 0.f));
            *(uint4*)(&Af[fi * 8]) = *(const uint4*)o;
        }
        __syncthreads();

        floatx4 acc[4][4];                          // bias pre-folded
#pragma unroll
        for (int rt = 0; rt < 4; rt++)
#pragma unroll
            for (int ct = 0; ct < 4; ct++) {
                acc[rt][ct][0] = bb[ct]; acc[rt][ct][1] = bb[ct];
                acc[rt][ct][2] = bb[ct]; acc[rt][ct][3] = bb[ct];
            }

#pragma unroll
        for (int step = 0; step < 8; step++) {
            const u16* Wk = W2f + ((size_t)((k * 8 + step) * 16 + wave * 4)) * 512;
            bf16x8 bfr[4], af[4];
#pragma unroll
            for (int ct = 0; ct < 4; ct++)
                bfr[ct] = *(const bf16x8*)(Wk + ct * 512 + lane * 8);
#pragma unroll
            for (int rt = 0; rt < 4; rt++)
                af[rt] = *(const bf16x8*)(&Af[((step * 4 + rt) * 64 + lane) * 8]);
#pragma unroll
            for (int rt = 0; rt < 4; rt++)
#pragma unroll
                for (int ct = 0; ct < 4; ct++)
                    acc[rt][ct] = __builtin_amdgcn_mfma_f32_16x16x32_bf16(
                        af[rt], bfr[ct], acc[rt][ct], 0, 0, 0);
        }
        // epilogue: sum_j relu(C)*w  (C: col=lane&15, row=quad*4+reg)
        float4 wv[4];
#pragma unroll
        for (int rt = 0; rt < 4; rt++)
            wv[rt] = *(const float4*)&w_s[rt * 16 + lhi * 4];
#pragma unroll
        for (int ct = 0; ct < 4; ct++) {
            float p = 0.f;
#pragma unroll
            for (int rt = 0; rt < 4; rt++) {
                p += fmaxf(acc[rt][ct][0], 0.f) * wv[rt].x;
                p += fmaxf(acc[rt][ct][1], 0.f) * wv[rt].y;
                p += fmaxf(acc[rt][ct][2], 0.f) * wv[rt].z;
                p += fmaxf(acc[rt][ct][3], 0.f) * wv[rt].w;
            }
            p += __shfl_xor(p, 16, 64);
            p += __shfl_xor(p, 32, 64);
            if (lhi == 0) agg_s[colBase + ct * 16 + lane] += p;  // wave-private cols
        }
    }
    // tid reads its own wave's columns: no barrier needed
    agg[(size_t)blk * 256 + tid] = agg_s[tid];
}

// ---------------- K4: out-MLP (280->256->256->24) + residual + q, one block per b ----------------
__global__ void out_mlp(const float* __restrict__ x0, const float* __restrict__ agg,
                        const u16* __restrict__ Wo1f, const u16* __restrict__ Wo2f,
                        const u16* __restrict__ Wo3f,
                        const float* __restrict__ bo1, const float* __restrict__ bo2,
                        const float* __restrict__ bo3,
                        const float* __restrict__ Wq2, const float* __restrict__ bq2,
                        const float* __restrict__ Wq3, const float* __restrict__ bq3,
                        float* __restrict__ out) {
    int b = blockIdx.x;
    int tid = threadIdx.x;
    int lane = tid & 63, wave = tid >> 6;
    const int colBase = wave * 64;
    const int lhi = lane >> 4;
    __shared__ __align__(16) u16 A1f[2304 * 8];
    __shared__ __align__(16) u16 A2f[2048 * 8];
    __shared__ __align__(16) u16 h2f[2048 * 8];
    __shared__ float qs[4];

#pragma unroll
    for (int it = 0; it < 9; it++) {
        int fi = tid + 256 * it;
        int lane_f = fi & 63, frag = fi >> 6;
        int s = frag >> 2, rt = frag & 3;
        int m = rt * 16 + (lane_f & 15);
        int c0 = s * 32 + (lane_f >> 4) * 8;
        float vals[8];
        if (c0 < 24) {
            const float4* xr = (const float4*)(x0 + (b * 64 + m) * 24 + c0);
            float4 a = xr[0], c = xr[1];
            vals[0] = a.x; vals[1] = a.y; vals[2] = a.z; vals[3] = a.w;
            vals[4] = c.x; vals[5] = c.y; vals[6] = c.z; vals[7] = c.w;
        } else if (c0 < 280) {
            const float4* ar = (const float4*)(agg + ((size_t)(b * 64 + m)) * 256 + (c0 - 24));
            float4 a = ar[0], c = ar[1];
            vals[0] = a.x; vals[1] = a.y; vals[2] = a.z; vals[3] = a.w;
            vals[4] = c.x; vals[5] = c.y; vals[6] = c.z; vals[7] = c.w;
        } else {
#pragma unroll
            for (int q = 0; q < 8; q++) vals[q] = 0.f;
        }
        unsigned o[4];
#pragma unroll
        for (int jp = 0; jp < 4; jp++) o[jp] = pk2(vals[jp * 2], vals[jp * 2 + 1]);
        *(uint4*)(&A1f[fi * 8]) = *(uint4*)o;
    }
    __syncthreads();

    floatx4 acc[4][4];
#pragma unroll
    for (int rt = 0; rt < 4; rt++)
#pragma unroll
        for (int ct = 0; ct < 4; ct++)
#pragma unroll
            for (int q = 0; q < 4; q++) acc[rt][ct][q] = 0.f;
#pragma unroll
    for (int step = 0; step < 9; step++) {
        const u16* Wk = Wo1f + ((size_t)(step * 16 + wave * 4)) * 512;
        bf16x8 bfr[4], af[4];
#pragma unroll
        for (int ct = 0; ct < 4; ct++) bfr[ct] = *(const bf16x8*)(Wk + ct * 512 + lane * 8);
#pragma unroll
        for (int rt = 0; rt < 4; rt++) af[rt] = *(const bf16x8*)(&A1f[((step * 4 + rt) * 64 + lane) * 8]);
#pragma unroll
        for (int rt = 0; rt < 4; rt++)
#pragma unroll
            for (int ct = 0; ct < 4; ct++)
                acc[rt][ct] = __builtin_amdgcn_mfma_f32_16x16x32_bf16(af[rt], bfr[ct], acc[rt][ct], 0, 0, 0);
    }
#pragma unroll
    for (int ct = 0; ct < 4; ct++) {
        int col = colBase + ct * 16 + (lane & 15);
        float bbv = bo1[col];
        int s2 = col >> 5, jj = col & 7, lf_hi = ((col >> 3) & 3) << 4;
#pragma unroll
        for (int rt = 0; rt < 4; rt++)
#pragma unroll
            for (int reg = 0; reg < 4; reg++) {
                int row = rt * 16 + lhi * 4 + reg;
                int lane_f = (row & 15) | lf_hi;
                A2f[((s2 * 4 + rt) * 64 + lane_f) * 8 + jj] = f2b(fmaxf(acc[rt][ct][reg] + bbv, 0.f));
            }
    }
    __syncthreads();

#pragma unroll
    for (int rt = 0; rt < 4; rt++)
#pragma unroll
        for (int ct = 0; ct < 4; ct++)
#pragma unroll
            for (int q = 0; q < 4; q++) acc[rt][ct][q] = 0.f;
#pragma unroll
    for (int step = 0; step < 8; step++) {
        const u16* Wk = Wo2f + ((size_t)(step * 16 + wave * 4)) * 512;
        bf16x8 bfr[4], af[4];
#pragma unroll
        for (int ct = 0; ct < 4; ct++) bfr[ct] = *(const bf16x8*)(Wk + ct * 512 + lane * 8);
#pragma unroll
        for (int rt = 0; rt < 4; rt++) af[rt] = *(const bf16x8*)(&A2f[((step * 4 + rt) * 64 + lane) * 8]);
#pragma unroll
        for (int rt = 0; rt < 4; rt++)
#pragma unroll
            for (int ct = 0; ct < 4; ct++)
                acc[rt][ct] = __builtin_amdgcn_mfma_f32_16x16x32_bf16(af[rt], bfr[ct], acc[rt][ct], 0, 0, 0);
    }
#pragma unroll
    for (int ct = 0; ct < 4; ct++) {
        int col = colBase + ct * 16 + (lane & 15);
        float bbv = bo2[col];
        int s2 = col >> 5, jj = col & 7, lf_hi = ((col >> 3) & 3) << 4;
#pragma unroll
        for (int rt = 0; rt < 4; rt++)
#pragma unroll
            for (int reg = 0; reg < 4; reg++) {
                int row = rt * 16 + lhi * 4 + reg;
                int lane_f = (row & 15) | lf_hi;
                h2f[((s2 * 4 + rt) * 64 + lane_f) * 8 + jj] = f2b(fmaxf(acc[rt][ct][reg] + bbv, 0.f));
            }
    }
    __syncthreads();

    floatx4 acc3[2];
#pragma unroll
    for (int ct = 0; ct < 2; ct++)
#pragma unroll
        for (int q = 0; q < 4; q++) acc3[ct][q] = 0.f;
#pragma unroll
    for (int step = 0; step < 8; step++) {
        bf16x8 af = *(const bf16x8*)(&h2f[((step * 4 + wave) * 64 + lane) * 8]);
#pragma unroll
        for (int ct = 0; ct < 2; ct++) {
            bf16x8 bfr = *(const bf16x8*)(Wo3f + ((size_t)(step * 2 + ct)) * 512 + lane * 8);
            acc3[ct] = __builtin_amdgcn_mfma_f32_16x16x32_bf16(af, bfr, acc3[ct], 0, 0, 0);
        }
    }
    float pr[4];
#pragma unroll
    for (int reg = 0; reg < 4; reg++) {
        float p = 0.f;
#pragma unroll
        for (int ct = 0; ct < 2; ct++) {
            int col = ct * 16 + (lane & 15);
            if (col < 24) {
                int row = wave * 16 + lhi * 4 + reg;
                float val = acc3[ct][reg] + bo3[col] + x0[(b * 64 + row) * 24 + col];
                p += val * Wq2[col];
            }
        }
        pr[reg] = p;
    }
#pragma unroll
    for (int off = 1; off <= 8; off <<= 1)
#pragma unroll
        for (int reg = 0; reg < 4; reg++) pr[reg] += __shfl_xor(pr[reg], off, 64);
    float contrib = 0.f;
    if ((lane & 15) == 0) {
#pragma unroll
        for (int reg = 0; reg < 4; reg++) {
            int row = wave * 16 + lhi * 4 + reg;
            contrib += (pr[reg] + bq2[0]) * Wq3[row];
        }
    }
    contrib += __shfl_xor(contrib, 16, 64);
    contrib += __shfl_xor(contrib, 32, 64);
    if (lane == 0) qs[wave] = contrib;
    __syncthreads();
    if (tid == 0) out[b] = bq3[0] + qs[0] + qs[1] + qs[2] + qs[3];
}

extern "C" void kernel_launch(void* const* d_in, const int* in_sizes, int n_in,
                              void* d_out, int out_size, void* d_ws, size_t ws_size,
                              hipStream_t stream) {
    const float* data = (const float*)d_in[0];
    const float* act  = (const float*)d_in[1];
    const float* edges = (const float*)d_in[2];
    // d_in[3] rel_rec, d_in[4] rel_send, d_in[5] prediction_steps: structure hardcoded (steps=1)
    const float* Wm1 = (const float*)d_in[6];
    const float* bm1 = (const float*)d_in[7];
    const float* Wm2 = (const float*)d_in[8];
    const float* bm2 = (const float*)d_in[9];
    const float* Wo1 = (const float*)d_in[10];
    const float* bo1 = (const float*)d_in[11];
    const float* Wo2 = (const float*)d_in[12];
    const float* bo2 = (const float*)d_in[13];
    const float* Wo3 = (const float*)d_in[14];
    const float* bo3 = (const float*)d_in[15];
    const float* Wq2 = (const float*)d_in[16];
    const float* bq2 = (const float*)d_in[17];
    const float* Wq3 = (const float*)d_in[18];
    const float* bq3 = (const float*)d_in[19];
    float* out = (float*)d_out;

    char* ws = (char*)d_ws;
    size_t off = 0;
    auto carve = [&](size_t bytes) -> void* {
        void* p = ws + off;
        off += (bytes + 255) & ~(size_t)255;
        return p;
    };
    u16*   u1   = (u16*)carve((size_t)64 * 64 * 2 * 256 * 2);   // 4 MB, row order
    u16*   u2   = (u16*)carve((size_t)64 * 64 * 2 * 256 * 2);   // 4 MB
    float* x0   = (float*)carve((size_t)64 * 64 * 24 * 4);
    float* agg  = (float*)carve((size_t)64 * 64 * 256 * 4);     // 4 MB
    u16*   W2f  = (u16*)carve((size_t)2 * 8 * 16 * 64 * 8 * 2);
    u16*   Wo1f = (u16*)carve((size_t)9 * 16 * 64 * 8 * 2);
    u16*   Wo2f = (u16*)carve((size_t)8 * 16 * 64 * 8 * 2);
    u16*   Wo3f = (u16*)carve((size_t)8 * 2 * 64 * 8 * 2);

    prep_and_u<<<dim3(290), dim3(256), 0, stream>>>(Wm2, Wo1, Wo2, Wo3, W2f, Wo1f, Wo2f, Wo3f,
                                                    data, act, Wm1, bm1, x0, u1, u2);
    edge_kernel<<<dim3(4096), dim3(256), 0, stream>>>(u1, u2, edges, W2f, bm2, agg);
    out_mlp<<<dim3(64), dim3(256), 0, stream>>>(x0, agg, Wo1f, Wo2f, Wo3f, bo1, bo2, bo3,
                                                Wq2, bq2, Wq3, bq3, out);
}

// Round 5
// 214.556 us; speedup vs baseline: 1.4614x; 1.0097x over previous
//
#include <hip/hip_runtime.h>

typedef _Float16 f16;
typedef __attribute__((ext_vector_type(8))) _Float16 f16x8;
typedef __attribute__((ext_vector_type(4))) float floatx4;

union H8 { f16 h[8]; uint4 v; };

#if defined(__has_builtin)
#if __has_builtin(__builtin_elementwise_max)
#define HAVE_EMAX 1
#endif
#endif

__device__ __forceinline__ f16x8 relu8(f16x8 x) {
    f16x8 z = {};
#ifdef HAVE_EMAX
    return __builtin_elementwise_max(x, z);
#else
    f16x8 r;
#pragma unroll
    for (int j = 0; j < 8; j++) r[j] = x[j] > (f16)0 ? x[j] : (f16)0;
    return r;
#endif
}

// ---------------- P0 (fused): weight prep (fp16 frag tables) + x0/u1/u2 ----------------
// Blocks 0..33: weight tables.  Blocks 34..289: compute_u.
// Frag entry (s, nt, lane, j) = B[kk = s*32 + (lane>>4)*8 + j][n = nt*16 + (lane&15)]
// W2f: [k2][s<8][nt<16][l][8]; Wo1f: [s<9][nt<16][l][8] (K pad 280->288);
// Wo2f: [s<8][nt<16][l][8];    Wo3f: [s<8][nt<2][l][8]  (N pad 24->32)
__global__ void prep_and_u(const float* __restrict__ Wm2, const float* __restrict__ Wo1,
                           const float* __restrict__ Wo2, const float* __restrict__ Wo3,
                           f16* __restrict__ W2f, f16* __restrict__ Wo1f,
                           f16* __restrict__ Wo2f, f16* __restrict__ Wo3f,
                           const float* __restrict__ data, const float* __restrict__ act,
                           const float* __restrict__ Wm1, const float* __restrict__ bm1,
                           float* __restrict__ x0, f16* __restrict__ u1, f16* __restrict__ u2) {
    __shared__ float tile[32 * 257];
    __shared__ float t3[256 * 25];
    int id = blockIdx.x;
    int tid = threadIdx.x;
    if (id < 33) {
        const float* src; f16* dst; int s, Ksrc;
        if (id < 16)      { int k = id >> 3; s = id & 7; src = Wm2 + k * 65536; dst = W2f + k * 65536; Ksrc = 256; }
        else if (id < 25) { s = id - 16; src = Wo1; dst = Wo1f; Ksrc = 280; }
        else              { s = id - 25; src = Wo2; dst = Wo2f; Ksrc = 256; }
        int kk0 = s * 32;
        for (int t = tid; t < 32 * 256; t += 256) {
            int r = t >> 8, c = t & 255;
            tile[r * 257 + c] = (kk0 + r < Ksrc) ? src[(size_t)(kk0 + r) * 256 + c] : 0.f;
        }
        __syncthreads();
#pragma unroll
        for (int it = 0; it < 4; it++) {
            int t = tid + 256 * it;                  // 0..1023 = (nt, l)
            int nt = t >> 6, l = t & 63;
            int n = nt * 16 + (l & 15), q = l >> 4;
            H8 o;
#pragma unroll
            for (int j = 0; j < 8; j++) o.h[j] = (f16)tile[(q * 8 + j) * 257 + n];
            *(uint4*)(dst + ((size_t)(s * 16 + nt)) * 512 + l * 8) = o.v;
        }
    } else if (id == 33) {
        for (int t = tid; t < 256 * 24; t += 256) {
            int r = t / 24, c = t - r * 24;
            t3[r * 25 + c] = Wo3[t];
        }
        __syncthreads();
#pragma unroll
        for (int it = 0; it < 4; it++) {
            int e = tid + 256 * it;                  // 0..1023 = ((s*2+nt)*64 + l)
            int s3 = e >> 7, nt = (e >> 6) & 1, l = e & 63;
            int n = nt * 16 + (l & 15), q = l >> 4;
            H8 o;
#pragma unroll
            for (int j = 0; j < 8; j++) {
                int kk = s3 * 32 + q * 8 + j;
                o.h[j] = (f16)((n < 24) ? t3[kk * 25 + n] : 0.f);
            }
            *(uint4*)(Wo3f + (size_t)e * 8) = o.v;
        }
    } else {
        // ---- compute_u: u1[b,n,k,h] = x0·W1[k][0:24,h]; u2 = x0·W1[k][24:48,h]+b1 ----
        int r0 = (id - 34) * 16;
        float* xs = tile;
        for (int idx = tid; idx < 16 * 24; idx += 256) {
            int rr = idx / 24, d = idx - rr * 24;
            int r = r0 + rr;
            float v = (d < 16) ? data[(r * 2) * 16 + d]       // t=0 only (output keeps t=0)
                               : act[(r * 2) * 8 + (d - 16)];
            xs[rr * 24 + d] = v;
            x0[r * 24 + d] = v;
        }
        __syncthreads();
        int h = tid;
        float acc[4][16];
#pragma unroll
        for (int q = 0; q < 4; q++)
#pragma unroll
            for (int rr = 0; rr < 16; rr++) acc[q][rr] = 0.f;
#pragma unroll
        for (int d = 0; d < 24; d++) {
            float w10 = Wm1[(0 * 48 + d) * 256 + h];
            float w11 = Wm1[(1 * 48 + d) * 256 + h];
            float w20 = Wm1[(0 * 48 + 24 + d) * 256 + h];
            float w21 = Wm1[(1 * 48 + 24 + d) * 256 + h];
#pragma unroll
            for (int rr = 0; rr < 16; rr++) {
                float x = xs[rr * 24 + d];
                acc[0][rr] += x * w10;
                acc[1][rr] += x * w11;
                acc[2][rr] += x * w20;
                acc[3][rr] += x * w21;
            }
        }
        float bb0 = bm1[h], bb1 = bm1[256 + h];
#pragma unroll
        for (int rr = 0; rr < 16; rr++) {
            int r = r0 + rr;
            u1[((size_t)r * 2 + 0) * 256 + h] = (f16)acc[0][rr];
            u1[((size_t)r * 2 + 1) * 256 + h] = (f16)acc[1][rr];
            u2[((size_t)r * 2 + 0) * 256 + h] = (f16)(acc[2][rr] + bb0);
            u2[((size_t)r * 2 + 1) * 256 + h] = (f16)(acc[3][rr] + bb1);
        }
    }
}

// ---------------- K3: edge MLP layer-2 + weighted aggregate ----------------
// block = (b,i). A = relu(u1[b,j,k]+u2[b,i,k]) staged in LDS in A-fragment order
// with packed fp16 math + strength-reduced addressing; B frags global->reg (L2-hit).
__global__ __launch_bounds__(256, 3) void edge_kernel(
    const f16* __restrict__ u1, const f16* __restrict__ u2, const float* __restrict__ edges,
    const f16* __restrict__ W2f, const float* __restrict__ bm2, float* __restrict__ agg) {
    int blk = blockIdx.x;
    int b = blk >> 6, i = blk & 63;
    __shared__ __align__(16) f16 Af[2048 * 8];    // 32 KB: [s<8][rt<4][lane][8]
    __shared__ float agg_s[256];                  // wave-private column ranges
    __shared__ float w_s[64];
    int tid = threadIdx.x;
    int lane = tid & 63, wave = tid >> 6;
    agg_s[tid] = 0.f;
    const int colBase = wave * 64;
    const int lhi = lane >> 4;
    // staging decode collapses: s=it, rt=wave, lane_f=lane -> fixed row j, strided c0
    const int jrow = wave * 16 + (lane & 15);
    const int lhi8 = lhi * 8;

#pragma unroll 1
    for (int k = 0; k < 2; k++) {
        __syncthreads();                 // all waves done with Af/w_s of prev k
        if (tid < 64) {
            int j = tid;
            float w = 0.f;
            if (j != i) {
                int jj = j - (j > i ? 1 : 0);
                w = edges[((size_t)b * 4032 + (size_t)i * 63 + jj) * 2 + k];
            }
            w_s[j] = w;
        }
        float bb[4];
#pragma unroll
        for (int ct = 0; ct < 4; ct++) bb[ct] = bm2[k * 256 + colBase + ct * 16 + (lane & 15)];
        const f16* pu1 = u1 + (size_t)b * 32768 + k * 256 + jrow * 512 + lhi8;
        const f16* pu2 = u2 + (size_t)b * 32768 + k * 256 + i * 512 + lhi8;
        f16* pAf = &Af[tid * 8];
#pragma unroll
        for (int it = 0; it < 8; it++) {
            f16x8 av = *(const f16x8*)(pu1 + it * 32);
            f16x8 uv = *(const f16x8*)(pu2 + it * 32);
            *(f16x8*)(pAf + it * 2048) = relu8(av + uv);
        }
        __syncthreads();

        floatx4 acc[4][4];                          // bias pre-folded
#pragma unroll
        for (int rt = 0; rt < 4; rt++)
#pragma unroll
            for (int ct = 0; ct < 4; ct++) {
                acc[rt][ct][0] = bb[ct]; acc[rt][ct][1] = bb[ct];
                acc[rt][ct][2] = bb[ct]; acc[rt][ct][3] = bb[ct];
            }

#pragma unroll
        for (int step = 0; step < 8; step++) {
            const f16* Wk = W2f + ((size_t)((k * 8 + step) * 16 + wave * 4)) * 512;
            f16x8 bfr[4], af[4];
#pragma unroll
            for (int ct = 0; ct < 4; ct++)
                bfr[ct] = *(const f16x8*)(Wk + ct * 512 + lane * 8);
#pragma unroll
            for (int rt = 0; rt < 4; rt++)
                af[rt] = *(const f16x8*)(&Af[((step * 4 + rt) * 64 + lane) * 8]);
#pragma unroll
            for (int rt = 0; rt < 4; rt++)
#pragma unroll
                for (int ct = 0; ct < 4; ct++)
                    acc[rt][ct] = __builtin_amdgcn_mfma_f32_16x16x32_f16(
                        af[rt], bfr[ct], acc[rt][ct], 0, 0, 0);
        }
        // epilogue: sum_j relu(C)*w  (C: col=lane&15, row=quad*4+reg)
        float4 wv[4];
#pragma unroll
        for (int rt = 0; rt < 4; rt++)
            wv[rt] = *(const float4*)&w_s[rt * 16 + lhi * 4];
#pragma unroll
        for (int ct = 0; ct < 4; ct++) {
            float p = 0.f;
#pragma unroll
            for (int rt = 0; rt < 4; rt++) {
                p += fmaxf(acc[rt][ct][0], 0.f) * wv[rt].x;
                p += fmaxf(acc[rt][ct][1], 0.f) * wv[rt].y;
                p += fmaxf(acc[rt][ct][2], 0.f) * wv[rt].z;
                p += fmaxf(acc[rt][ct][3], 0.f) * wv[rt].w;
            }
            p += __shfl_xor(p, 16, 64);
            p += __shfl_xor(p, 32, 64);
            if (lhi == 0) agg_s[colBase + ct * 16 + lane] += p;  // wave-private cols
        }
    }
    agg[(size_t)blk * 256 + tid] = agg_s[tid];
}

// ---------------- K4: out-MLP, 4 blocks per batch (M=16 rows each) ----------------
__global__ void out_mlp(const float* __restrict__ x0, const float* __restrict__ agg,
                        const f16* __restrict__ Wo1f, const f16* __restrict__ Wo2f,
                        const f16* __restrict__ Wo3f,
                        const float* __restrict__ bo1, const float* __restrict__ bo2,
                        const float* __restrict__ bo3,
                        const float* __restrict__ Wq2, const float* __restrict__ bq2,
                        const float* __restrict__ Wq3, const float* __restrict__ bq3,
                        float* __restrict__ out) {
    int blk = blockIdx.x;
    int b = blk >> 2, n0 = (blk & 3) * 16;
    int tid = threadIdx.x;
    int lane = tid & 63, wave = tid >> 6;
    const int colBase = wave * 64;
    const int lhi = lane >> 4;
    __shared__ __align__(16) f16 A1f[9 * 64 * 8];   // 9 KB
    __shared__ __align__(16) f16 A2f[8 * 64 * 8];   // 8 KB
    __shared__ __align__(16) f16 h2f[8 * 64 * 8];   // 8 KB
    __shared__ float pq[16][2];

    // stage aug = [x0(24) | agg(256) | pad(8)] rows n0..n0+15 in A-frag order
    for (int t = tid; t < 576; t += 256) {
        int lane_f = t & 63, s = t >> 6;
        int m = n0 + (lane_f & 15);
        int c0 = s * 32 + (lane_f >> 4) * 8;
        float vals[8];
        if (c0 < 24) {
            const float4* xr = (const float4*)(x0 + (b * 64 + m) * 24 + c0);
            float4 a = xr[0], c = xr[1];
            vals[0] = a.x; vals[1] = a.y; vals[2] = a.z; vals[3] = a.w;
            vals[4] = c.x; vals[5] = c.y; vals[6] = c.z; vals[7] = c.w;
        } else if (c0 < 280) {
            const float4* ar = (const float4*)(agg + ((size_t)(b * 64 + m)) * 256 + (c0 - 24));
            float4 a = ar[0], c = ar[1];
            vals[0] = a.x; vals[1] = a.y; vals[2] = a.z; vals[3] = a.w;
            vals[4] = c.x; vals[5] = c.y; vals[6] = c.z; vals[7] = c.w;
        } else {
#pragma unroll
            for (int q = 0; q < 8; q++) vals[q] = 0.f;
        }
        H8 o;
#pragma unroll
        for (int q = 0; q < 8; q++) o.h[q] = (f16)vals[q];
        *(uint4*)(&A1f[t * 8]) = o.v;
    }
    __syncthreads();

    // layer 1: M=16, N=256, K=288 (9 steps); wave owns cols wave*64..+63
    floatx4 acc[4];
#pragma unroll
    for (int ct = 0; ct < 4; ct++)
#pragma unroll
        for (int q = 0; q < 4; q++) acc[ct][q] = 0.f;
#pragma unroll
    for (int step = 0; step < 9; step++) {
        f16x8 af = *(const f16x8*)(&A1f[(step * 64 + lane) * 8]);
#pragma unroll
        for (int ct = 0; ct < 4; ct++) {
            f16x8 bfr = *(const f16x8*)(Wo1f + ((size_t)(step * 16 + wave * 4 + ct)) * 512 + lane * 8);
            acc[ct] = __builtin_amdgcn_mfma_f32_16x16x32_f16(af, bfr, acc[ct], 0, 0, 0);
        }
    }
#pragma unroll
    for (int ct = 0; ct < 4; ct++) {   // h1 = relu(C+bo1) -> A2f
        int col = colBase + ct * 16 + (lane & 15);
        float bbv = bo1[col];
        int s2 = col >> 5, jj = col & 7, lf_hi = ((col >> 3) & 3) << 4;
#pragma unroll
        for (int reg = 0; reg < 4; reg++) {
            int row = lhi * 4 + reg;
            A2f[(s2 * 64 + (row | lf_hi)) * 8 + jj] = (f16)fmaxf(acc[ct][reg] + bbv, 0.f);
        }
    }
    __syncthreads();

    // layer 2: M=16, N=256, K=256 (8 steps)
#pragma unroll
    for (int ct = 0; ct < 4; ct++)
#pragma unroll
        for (int q = 0; q < 4; q++) acc[ct][q] = 0.f;
#pragma unroll
    for (int step = 0; step < 8; step++) {
        f16x8 af = *(const f16x8*)(&A2f[(step * 64 + lane) * 8]);
#pragma unroll
        for (int ct = 0; ct < 4; ct++) {
            f16x8 bfr = *(const f16x8*)(Wo2f + ((size_t)(step * 16 + wave * 4 + ct)) * 512 + lane * 8);
            acc[ct] = __builtin_amdgcn_mfma_f32_16x16x32_f16(af, bfr, acc[ct], 0, 0, 0);
        }
    }
#pragma unroll
    for (int ct = 0; ct < 4; ct++) {   // h2 = relu(C+bo2) -> h2f
        int col = colBase + ct * 16 + (lane & 15);
        float bbv = bo2[col];
        int s2 = col >> 5, jj = col & 7, lf_hi = ((col >> 3) & 3) << 4;
#pragma unroll
        for (int reg = 0; reg < 4; reg++) {
            int row = lhi * 4 + reg;
            h2f[(s2 * 64 + (row | lf_hi)) * 8 + jj] = (f16)fmaxf(acc[ct][reg] + bbv, 0.f);
        }
    }
    __syncthreads();

    // layer 3: M=16, N=32(24), K=256; waves 0/1 handle col-tiles 0/1
    if (wave < 2) {
        floatx4 acc3;
#pragma unroll
        for (int q = 0; q < 4; q++) acc3[q] = 0.f;
#pragma unroll
        for (int step = 0; step < 8; step++) {
            f16x8 af = *(const f16x8*)(&h2f[(step * 64 + lane) * 8]);
            f16x8 bfr = *(const f16x8*)(Wo3f + ((size_t)(step * 2 + wave)) * 512 + lane * 8);
            acc3 = __builtin_amdgcn_mfma_f32_16x16x32_f16(af, bfr, acc3, 0, 0, 0);
        }
        int col = wave * 16 + (lane & 15);
        float pr[4];
#pragma unroll
        for (int reg = 0; reg < 4; reg++) {
            float p = 0.f;
            if (col < 24) {
                int row = lhi * 4 + reg;
                float val = acc3[reg] + bo3[col] + x0[(b * 64 + n0 + row) * 24 + col];
                p = val * Wq2[col];
            }
            pr[reg] = p;
        }
#pragma unroll
        for (int off = 1; off <= 8; off <<= 1)
#pragma unroll
            for (int reg = 0; reg < 4; reg++) pr[reg] += __shfl_xor(pr[reg], off, 64);
        if ((lane & 15) == 0) {
#pragma unroll
            for (int reg = 0; reg < 4; reg++) pq[lhi * 4 + reg][wave] = pr[reg];
        }
    }
    __syncthreads();
    if (tid == 0) {
        float s = ((blk & 3) == 0) ? bq3[0] : 0.f;
#pragma unroll
        for (int r = 0; r < 16; r++)
            s += (pq[r][0] + pq[r][1] + bq2[0]) * Wq3[n0 + r];
        atomicAdd(out + b, s);
    }
}

extern "C" void kernel_launch(void* const* d_in, const int* in_sizes, int n_in,
                              void* d_out, int out_size, void* d_ws, size_t ws_size,
                              hipStream_t stream) {
    const float* data = (const float*)d_in[0];
    const float* act  = (const float*)d_in[1];
    const float* edges = (const float*)d_in[2];
    // d_in[3] rel_rec, d_in[4] rel_send, d_in[5] prediction_steps: structure hardcoded (steps=1)
    const float* Wm1 = (const float*)d_in[6];
    const float* bm1 = (const float*)d_in[7];
    const float* Wm2 = (const float*)d_in[8];
    const float* bm2 = (const float*)d_in[9];
    const float* Wo1 = (const float*)d_in[10];
    const float* bo1 = (const float*)d_in[11];
    const float* Wo2 = (const float*)d_in[12];
    const float* bo2 = (const float*)d_in[13];
    const float* Wo3 = (const float*)d_in[14];
    const float* bo3 = (const float*)d_in[15];
    const float* Wq2 = (const float*)d_in[16];
    const float* bq2 = (const float*)d_in[17];
    const float* Wq3 = (const float*)d_in[18];
    const float* bq3 = (const float*)d_in[19];
    float* out = (float*)d_out;

    char* ws = (char*)d_ws;
    size_t off = 0;
    auto carve = [&](size_t bytes) -> void* {
        void* p = ws + off;
        off += (bytes + 255) & ~(size_t)255;
        return p;
    };
    f16*   u1   = (f16*)carve((size_t)64 * 64 * 2 * 256 * 2);   // 4 MB, row order
    f16*   u2   = (f16*)carve((size_t)64 * 64 * 2 * 256 * 2);   // 4 MB
    float* x0   = (float*)carve((size_t)64 * 64 * 24 * 4);
    float* agg  = (float*)carve((size_t)64 * 64 * 256 * 4);     // 4 MB
    f16*   W2f  = (f16*)carve((size_t)2 * 8 * 16 * 64 * 8 * 2);
    f16*   Wo1f = (f16*)carve((size_t)9 * 16 * 64 * 8 * 2);
    f16*   Wo2f = (f16*)carve((size_t)8 * 16 * 64 * 8 * 2);
    f16*   Wo3f = (f16*)carve((size_t)8 * 2 * 64 * 8 * 2);

    hipMemsetAsync(d_out, 0, 64 * sizeof(float), stream);
    prep_and_u<<<dim3(290), dim3(256), 0, stream>>>(Wm2, Wo1, Wo2, Wo3, W2f, Wo1f, Wo2f, Wo3f,
                                                    data, act, Wm1, bm1, x0, u1, u2);
    edge_kernel<<<dim3(4096), dim3(256), 0, stream>>>(u1, u2, edges, W2f, bm2, agg);
    out_mlp<<<dim3(256), dim3(256), 0, stream>>>(x0, agg, Wo1f, Wo2f, Wo3f, bo1, bo2, bo3,
                                                 Wq2, bq2, Wq3, bq3, out);
}